// Round 1
// baseline (69.873 us; speedup 1.0000x reference)
//
#include <hip/hip_runtime.h>

// GaussianAdapter: out[b,r,f] = sum_t(w*v) / sum_t(w),
//   w = exp(-alpha*(r - ts)^2) * (ts>0) + EPS
// B=16, T=512, R=128, F=32. Compute-bound (33.5M exp ops), I/O ~2.25 MB.

constexpr int B_ = 16, T_ = 512, R_ = 128, F_ = 32;
constexpr int S_  = 4;          // T splits (occupancy: 1024 blocks -> 4 waves/SIMD)
constexpr int TS_ = T_ / S_;    // 128 timesteps per block
constexpr int RB_ = 8;          // r values per block (tile reuse factor)
constexpr float EPS_ = 1e-7f;

// Partial sums over one T-chunk. Block = 256 threads: f = tid&31, r_local = tid>>5.
__global__ __launch_bounds__(256) void ga_partial(
    const float* __restrict__ ts_g, const float* __restrict__ v_g,
    const float* __restrict__ ref_g, const float* __restrict__ alpha_g,
    float2* __restrict__ ws)
{
    // interleaved (ts, v) pairs: 128 t-rows x 32 f x 2 floats = 32 KB
    __shared__ float tile[TS_ * F_ * 2];

    const int tid = threadIdx.x;
    const int s   = blockIdx.x % S_;
    const int rb  = (blockIdx.x / S_) % (R_ / RB_);
    const int b   = blockIdx.x / (S_ * (R_ / RB_));
    const int f   = tid & 31;
    const int rl  = tid >> 5;
    const int r_idx = rb * RB_ + rl;

    const float r    = ref_g[b * R_ + r_idx];
    const float nega = -alpha_g[0];

    // ---- stage global -> LDS, folding the (ts>0) mask into a sentinel ----
    // sentinel 2e19: (-alpha)*d*d overflows to -inf, __expf(-inf) = 0 exactly.
    const float4* tsg4 = (const float4*)(ts_g + (size_t)(b * T_ + s * TS_) * F_);
    const float4* vg4  = (const float4*)(v_g  + (size_t)(b * T_ + s * TS_) * F_);
    #pragma unroll
    for (int i = tid; i < TS_ * F_ / 4; i += 256) {
        float4 a = tsg4[i];
        float4 w = vg4[i];
        a.x = (a.x > 0.f) ? a.x : 2e19f;
        a.y = (a.y > 0.f) ? a.y : 2e19f;
        a.z = (a.z > 0.f) ? a.z : 2e19f;
        a.w = (a.w > 0.f) ? a.w : 2e19f;
        float4* dst = (float4*)(tile + 8 * i);
        dst[0] = make_float4(a.x, w.x, a.y, w.y);
        dst[1] = make_float4(a.z, w.z, a.w, w.w);
    }
    __syncthreads();

    // ---- hot loop: one ds_read_b64 + 6 VALU + 1 v_exp per element ----
    const float2* t2 = (const float2*)tile;
    float num = 0.f, den = 0.f;
    #pragma unroll 8
    for (int t = 0; t < TS_; ++t) {
        float2 tv = t2[t * F_ + f];          // lanes 0-31 / 32-63 alias: free
        float d = r - tv.x;
        float e = __expf(nega * d * d);      // 0 if masked (sentinel -> -inf)
        float wgt = e + EPS_;
        den += wgt;
        num = fmaf(wgt, tv.y, num);
    }

    ws[(size_t)s * (B_ * R_ * F_) + (size_t)(b * R_ + r_idx) * F_ + f] =
        make_float2(num, den);
}

__global__ __launch_bounds__(256) void ga_combine(
    const float2* __restrict__ ws, float* __restrict__ out)
{
    int i = blockIdx.x * 256 + threadIdx.x;
    float num = 0.f, den = 0.f;
    #pragma unroll
    for (int s = 0; s < S_; ++s) {
        float2 p = ws[(size_t)s * (B_ * R_ * F_) + i];
        num += p.x;
        den += p.y;
    }
    out[i] = num / den;
}

extern "C" void kernel_launch(void* const* d_in, const int* in_sizes, int n_in,
                              void* d_out, int out_size, void* d_ws, size_t ws_size,
                              hipStream_t stream) {
    const float* timesteps = (const float*)d_in[0];   // (B,T,F)
    const float* values    = (const float*)d_in[1];   // (B,T,F)
    const float* ref_ts    = (const float*)d_in[2];   // (B,R)
    const float* alpha     = (const float*)d_in[3];   // (1,)
    float* out = (float*)d_out;                        // (B,R,F)
    float2* ws = (float2*)d_ws;                        // S * 65536 float2 = 2 MB

    ga_partial<<<B_ * (R_ / RB_) * S_, 256, 0, stream>>>(
        timesteps, values, ref_ts, alpha, ws);
    ga_combine<<<(B_ * R_ * F_) / 256, 256, 0, stream>>>(ws, out);
}